// Round 2
// baseline (117.484 us; speedup 1.0000x reference)
//
#include <hip/hip_runtime.h>
#include <math.h>

// DegreeQuantileConverter:
//   deg: (B,S,1) f32, q: (12,) f32 = [0,1,2,4,...,1024]  (fixed by problem spec:
//   MAX_DEGREE=1024 -> q[0]=0, q[i]=2^(i-1) for i=1..11)
//   out: (B,S,12) f32 = log(w + 1e-30), w = linear-interp 2-hot row
//   (idx = searchsorted_right(q,deg)-1 clipped to [0,10]); whole row = 0.0f
//   (log(1+1e-30)) when deg >= 1024.
//
// Memory-bound expand: 100.7 MB write + 8.4 MB read -> ~17 us floor @6.3TB/s.
// Previous best measured 118.9 us (~0.92 TB/s) -> NOT at the roofline.
//
// R3 = R2 with the compile fix: __builtin_nontemporal_store requires a native
// clang vector type, not HIP's float4 class. Store via
// float __attribute__((ext_vector_type(4))).
//
// R2 theory (untested so far): per-thread VALU/prologue overhead + 24.5k
// micro-block grid + L2 write churn, not HBM, is the limiter.
//  1. Grid-stride loop, grid capped at 2048 blocks (Guideline 11). 12 float4
//     iterations/thread amortize prologue; full occupancy at this VGPR count.
//  2. Exponent-bit searchsorted: q is powers of two, so
//        idx = clamp(exp(deg)+1, 0, 10), lo = 2^(idx-1), 1/(hi-lo) = 2^(1-idx)
//     built from float bits. Replaces 10x{v_cmp+3 v_cndmask} (40 VALU) and all
//     12 q loads with ~10 VALU. Power-of-2 reciprocal is exact; ref divisor
//     differs by +1e-10 (rel err <= 1e-10, negligible vs 1.38 absmax).
//  3. Nontemporal 16B stores: 100 MB streaming output never re-read; keep it
//     out of L2.
// Layout unchanged: one thread per output float4 (12%4==0 -> a 16B store
// never crosses a row), fully coalesced; 3 adjacent lanes share one deg.

#define LOG_EPS_F (-69.07755278982137f)  // logf(1e-30f)

typedef float f32x4 __attribute__((ext_vector_type(4)));

__global__ __launch_bounds__(256) void dqc_kernel(
    const float* __restrict__ deg_in,
    const float* __restrict__ q,       // unused: structure hard-coded (see hdr)
    f32x4* __restrict__ out,
    unsigned nvec)
{
    (void)q;
    const unsigned stride = gridDim.x * 256u;
    for (unsigned t = blockIdx.x * 256u + threadIdx.x; t < nvec; t += stride) {
        unsigned row  = t / 3u;            // magic-mul div by 3
        unsigned part = t - row * 3u;      // which float4 of the row (0..2)

        float deg = deg_in[row];

        // searchsorted(q, deg, 'right') - 1 via exponent bits:
        // deg in [2^(i-1), 2^i) -> idx = i ; deg in [0,1) -> idx = 0.
        unsigned bits = __float_as_uint(deg);
        int idx = (int)(bits >> 23) - 126;            // exponent + 1
        idx = idx < 0 ? 0 : (idx > 10 ? 10 : idx);    // clamp to [0, 10]

        // lo = q[idx] = (idx ? 2^(idx-1) : 0); 1/(hi-lo) = (idx ? 2^(1-idx) : 1)
        float lo  = (idx == 0) ? 0.0f
                               : __uint_as_float((unsigned)(idx + 126) << 23);
        float inv = (idx == 0) ? 1.0f
                               : __uint_as_float((unsigned)(128 - idx) << 23);

        float pos = (deg - lo) * inv;
        pos = fminf(fmaxf(pos, 0.0f), 1.0f);          // v_med3

        bool top      = (deg >= 1024.0f);             // whole row -> 0.0f
        bool in_range = (deg >= 0.0f) && !top;

        float w_lo = in_range ? (1.0f - pos) : 0.0f;
        float w_hi = in_range ? pos          : 0.0f;
        // fast log: v_log_f32 (log2) * ln2
        float lw_lo = __logf(w_lo + 1e-30f);
        float lw_hi = __logf(w_hi + 1e-30f);
        float fill  = LOG_EPS_F;
        if (top) { lw_lo = 0.0f; lw_hi = 0.0f; fill = 0.0f; }

        int j0 = (int)part * 4;
        f32x4 o;
#pragma unroll
        for (int u = 0; u < 4; ++u) {
            int j = j0 + u;
            float x = fill;
            x = (j == idx)     ? lw_lo : x;
            x = (j == idx + 1) ? lw_hi : x;
            o[u] = x;
        }
        __builtin_nontemporal_store(o, &out[t]);
    }
}

extern "C" void kernel_launch(void* const* d_in, const int* in_sizes, int n_in,
                              void* d_out, int out_size, void* d_ws, size_t ws_size,
                              hipStream_t stream) {
    const float* deg = (const float*)d_in[0];  // (B*S,) flat, 2,097,152
    const float* q   = (const float*)d_in[1];  // (12,)
    f32x4* out       = (f32x4*)d_out;          // (B*S*12,) f32, 12%4==0

    unsigned nvec   = (unsigned)(out_size / 4);     // 6,291,456 float4s
    unsigned want   = (nvec + 255u) / 256u;
    unsigned blocks = want < 2048u ? want : 2048u;  // grid-stride the rest

    dqc_kernel<<<blocks, 256, 0, stream>>>(deg, q, out, nvec);
}

// Round 3
// 117.257 us; speedup vs baseline: 1.0019x; 1.0019x over previous
//
#include <hip/hip_runtime.h>
#include <math.h>

// DegreeQuantileConverter:
//   deg: (B,S,1) f32, q: (12,) f32 = [0,1,2,4,...,1024]  (fixed by problem spec)
//   out: (B,S,12) f32 = log(w + 1e-30), w = linear-interp 2-hot row
//   (idx = searchsorted_right(q,deg)-1 clipped to [0,10]); whole row = 0.0f
//   when deg >= 1024.
//
// Roofline: 100.7 MB write + 8.4 MB read -> ~17 us kernel floor @6.3TB/s.
// Evidence so far:
//   R1 (heavy VALU, one-shot grid): dur 118.9
//   R2 (half the VALU, 2048-block grid-stride, nt stores): dur 117.5 (NEUTRAL)
//   rocprof top-5 = fillBuffer @6.2TB/s, our kernel <64us -> dur includes a
//   ~65us harness re-poison fill; inferred kernel ~52us = 2.1 TB/s.
// VALU count, grid shape, store cache-mode all ELIMINATED as limiters.
//
// R4 theory: exposed load latency. Loop body is load->compute->store with the
// load consumed immediately; compiler emits vmcnt(0) per iteration, so each
// wave completes one 1KB store per memory latency. Fix: unroll x4 with the 4
// independent deg loads issued before any compute/store (legal: __restrict__
// no-alias lets loads hoist past stores). 4x MLP/wave, ~30 VGPR (occupancy
// unchanged at full 32 waves/CU).
// Prediction: WRITE_SIZE/FETCH_SIZE unchanged; dur_us 117.5 -> 85-95 if
// latency theory holds (kernel 52 -> ~20-30); unchanged if refuted.

#define LOG_EPS_F (-69.07755278982137f)  // logf(1e-30f)

typedef float f32x4 __attribute__((ext_vector_type(4)));

__device__ __forceinline__ f32x4 dqc_item(float deg, unsigned part)
{
    // searchsorted(q, deg, 'right') - 1 via exponent bits:
    // deg in [2^(i-1), 2^i) -> idx = i ; deg in [0,1) -> idx = 0.
    unsigned bits = __float_as_uint(deg);
    int idx = (int)(bits >> 23) - 126;            // exponent + 1
    idx = idx < 0 ? 0 : (idx > 10 ? 10 : idx);    // clamp to [0, 10]
    // (negative deg gives a garbage idx, but then in_range=false -> weights 0
    //  -> whole row LOG_EPS regardless of idx, matching the reference)

    // lo = q[idx] = (idx ? 2^(idx-1) : 0); 1/(hi-lo) = (idx ? 2^(1-idx) : 1)
    float lo  = (idx == 0) ? 0.0f
                           : __uint_as_float((unsigned)(idx + 126) << 23);
    float inv = (idx == 0) ? 1.0f
                           : __uint_as_float((unsigned)(128 - idx) << 23);

    float pos = (deg - lo) * inv;
    pos = fminf(fmaxf(pos, 0.0f), 1.0f);          // v_med3

    bool top      = (deg >= 1024.0f);             // whole row -> 0.0f
    bool in_range = (deg >= 0.0f) && !top;

    float w_lo = in_range ? (1.0f - pos) : 0.0f;
    float w_hi = in_range ? pos          : 0.0f;
    float lw_lo = __logf(w_lo + 1e-30f);          // v_log_f32 * ln2
    float lw_hi = __logf(w_hi + 1e-30f);
    float fill  = LOG_EPS_F;
    if (top) { lw_lo = 0.0f; lw_hi = 0.0f; fill = 0.0f; }

    int j0 = (int)part * 4;
    f32x4 o;
#pragma unroll
    for (int u = 0; u < 4; ++u) {
        int j = j0 + u;
        float x = fill;
        x = (j == idx)     ? lw_lo : x;
        x = (j == idx + 1) ? lw_hi : x;
        o[u] = x;
    }
    return o;
}

__global__ __launch_bounds__(256) void dqc_kernel(
    const float* __restrict__ deg_in,
    const float* __restrict__ q,       // unused: structure hard-coded (see hdr)
    f32x4* __restrict__ out,
    unsigned nvec)
{
    (void)q;
    const unsigned stride = gridDim.x * 256u;
    const unsigned t0 = blockIdx.x * 256u + threadIdx.x;

    if (nvec == 12u * stride) {
        // Exact-shape fast path (nvec = 6,291,456 = 12 * 2048 * 256):
        // 3 outer iterations, each software-pipelined: 4 loads up front,
        // then 4 compute+store. No bounds checks.
        unsigned t = t0;
#pragma unroll 1
        for (int outer = 0; outer < 3; ++outer) {
            float    d[4];
            unsigned pp[4];
#pragma unroll
            for (int k = 0; k < 4; ++k) {
                unsigned tt = t + (unsigned)k * stride;
                unsigned r  = tt / 3u;           // magic-mul div by 3
                d[k]  = deg_in[r];
                pp[k] = tt - r * 3u;
            }
#pragma unroll
            for (int k = 0; k < 4; ++k) {
                f32x4 o = dqc_item(d[k], pp[k]);
                __builtin_nontemporal_store(o, &out[t + (unsigned)k * stride]);
            }
            t += 4u * stride;
        }
    } else {
        // Generic fallback
        for (unsigned t = t0; t < nvec; t += stride) {
            unsigned r = t / 3u;
            f32x4 o = dqc_item(deg_in[r], t - r * 3u);
            __builtin_nontemporal_store(o, &out[t]);
        }
    }
}

extern "C" void kernel_launch(void* const* d_in, const int* in_sizes, int n_in,
                              void* d_out, int out_size, void* d_ws, size_t ws_size,
                              hipStream_t stream) {
    const float* deg = (const float*)d_in[0];  // (B*S,) flat, 2,097,152
    const float* q   = (const float*)d_in[1];  // (12,)
    f32x4* out       = (f32x4*)d_out;          // (B*S*12,) f32, 12%4==0

    unsigned nvec   = (unsigned)(out_size / 4);     // 6,291,456 float4s
    unsigned want   = (nvec + 255u) / 256u;
    unsigned blocks = want < 2048u ? want : 2048u;  // grid-stride the rest

    dqc_kernel<<<blocks, 256, 0, stream>>>(deg, q, out, nvec);
}